// Round 7
// baseline (5188.342 us; speedup 1.0000x reference)
//
#include <hip/hip_runtime.h>
#include <hip/hip_cooperative_groups.h>

namespace cg = cooperative_groups;

#define TSTEPS 512
#define BATCH  64
#define DIN    256
#define HID    512
#define G4H    2048
#define NWG    128
#define UPW    4            // hidden units per workgroup (NWG*UPW == HID)
#define NTHR   256
#define KTOT   768          // D + H
#define WST    776          // Wt LDS row stride in bf16 elems (proven)
#define GST    17           // gate staging stride (floats)

typedef __attribute__((ext_vector_type(8))) short bf16x8;
typedef __attribute__((ext_vector_type(4))) float f32x4;

#define MFMA(A,B,C) __builtin_amdgcn_mfma_f32_16x16x32_bf16(A,B,C,0,0,0)
#define ALDU64(p) __hip_atomic_load(const_cast<unsigned long long*>(p), __ATOMIC_RELAXED, __HIP_MEMORY_SCOPE_AGENT)
#define ALDU32(p) __hip_atomic_load(const_cast<unsigned*>(p), __ATOMIC_RELAXED, __HIP_MEMORY_SCOPE_AGENT)
#define ASTU64(p,v) __hip_atomic_store((p), (v), __ATOMIC_RELAXED, __HIP_MEMORY_SCOPE_AGENT)
#define ASTU32(p,v) __hip_atomic_store((p), (v), __ATOMIC_RELAXED, __HIP_MEMORY_SCOPE_AGENT)

__device__ __forceinline__ unsigned short f2bf(float f) {
  unsigned u = __float_as_uint(f);
  u += 0x7fffu + ((u >> 16) & 1u);   // RNE truncate to bf16
  return (unsigned short)(u >> 16);
}
__device__ __forceinline__ float bf2f(unsigned short s) {
  return __uint_as_float((unsigned)s << 16);
}
__device__ __forceinline__ float sigm(float x) { return 1.0f / (1.0f + __expf(-x)); }

// One-time: split x (fp32) into hi/lo bf16 planes (proven).
__global__ void split_x_kernel(const float* __restrict__ x,
                               unsigned short* __restrict__ xhi,
                               unsigned short* __restrict__ xlo, int n4) {
  int i = blockIdx.x * blockDim.x + threadIdx.x;
  if (i >= n4) return;
  float4 v = reinterpret_cast<const float4*>(x)[i];
  unsigned short h0 = f2bf(v.x), h1 = f2bf(v.y), h2 = f2bf(v.z), h3 = f2bf(v.w);
  ushort4 hi = make_ushort4(h0, h1, h2, h3);
  ushort4 lo = make_ushort4(f2bf(v.x - bf2f(h0)), f2bf(v.y - bf2f(h1)),
                            f2bf(v.z - bf2f(h2)), f2bf(v.w - bf2f(h3)));
  reinterpret_cast<ushort4*>(xhi)[i] = hi;
  reinterpret_cast<ushort4*>(xlo)[i] = lo;
}

__global__ void __launch_bounds__(NTHR, 1)
lstm_persistent(const unsigned short* __restrict__ xhi,
                const unsigned short* __restrict__ xlo,
                const int* __restrict__ rst,
                const float* __restrict__ W,
                const float* __restrict__ bias,
                float* __restrict__ out,
                unsigned long long* __restrict__ hb,      // [2][BATCH][128] u64 (bf16x4)
                unsigned* __restrict__ flags) {           // [(wg*4+wave)*16] u32, 64B stride
  __shared__ unsigned short WtHi[16 * WST];
  __shared__ unsigned short WtLo[16 * WST];
  __shared__ float gateS[BATCH * GST];
  __shared__ float biasS[16];

  const int tid = threadIdx.x;
  const int wg  = blockIdx.x;
  const int j0  = wg * UPW;

  // --- prologue: W slice -> LDS (transposed, hi/lo), bias (proven) ---
  for (int flat = tid; flat < KTOT * 16; flat += NTHR) {
    int k = flat >> 4;
    int c = flat & 15;                        // LDS col: sec*4 + u
    int gcol = (c >> 2) * HID + j0 + (c & 3); // i|g|f|o sections of 4H
    float w = W[(size_t)k * G4H + gcol];
    unsigned short h = f2bf(w);
    WtHi[c * WST + k] = h;
    WtLo[c * WST + k] = f2bf(w - bf2f(h));
  }
  if (tid < 16) biasS[tid] = bias[(tid >> 2) * HID + j0 + (tid & 3)];
  __syncthreads();
  cg::grid_group grid = cg::this_grid();
  grid.sync();                              // once; proven launch config

  // --- per-thread geometry (proven) ---
  const int lane = tid & 63;
  const int wave = tid >> 6;
  const int r0   = wave * 16;
  const int arow = r0 + (lane & 15);
  const int klo  = (lane >> 4) * 8;
  const int colA = lane & 15;

  const unsigned short* bh_ = &WtHi[colA * WST + klo];
  const unsigned short* bl_ = &WtLo[colA * WST + klo];

  const int crow = r0 + lane;               // cell row (valid when lane < 16)
  float cReg[4] = {0.f, 0.f, 0.f, 0.f};

#define XPART(TT, A0) do {                                                      \
    const unsigned short* xrh_ = xhi + ((size_t)(TT) * BATCH + arow) * DIN + klo; \
    const unsigned short* xrl_ = xlo + ((size_t)(TT) * BATCH + arow) * DIN + klo; \
    _Pragma("unroll")                                                           \
    for (int kk = 0; kk < DIN / 32; ++kk) {                                     \
      int kb = kk * 32;                                                         \
      bf16x8 ah = *reinterpret_cast<const bf16x8*>(xrh_ + kb);                  \
      bf16x8 al = *reinterpret_cast<const bf16x8*>(xrl_ + kb);                  \
      bf16x8 bh = *reinterpret_cast<const bf16x8*>(bh_ + kb);                   \
      bf16x8 bl = *reinterpret_cast<const bf16x8*>(bl_ + kb);                   \
      A0 = MFMA(ah, bh, A0); A0 = MFMA(ah, bl, A0); A0 = MFMA(al, bh, A0);      \
    }                                                                           \
  } while (0)

  f32x4 accx = {0.f, 0.f, 0.f, 0.f};
  XPART(0, accx);
  int rstv = (lane < 16) ? rst[1 * BATCH + crow] : 0;
  f32x4 oStash = {0.f, 0.f, 0.f, 0.f};
  unsigned long long hq[32];                // pipelined h fragments (loop-carried)

  for (int t = 0; t < TSTEPS; ++t) {
    f32x4 accA = accx, accB = {0.f, 0.f, 0.f, 0.f};

    // ---- consume h(t) (loaded at end of previous iteration) ----
    if (t) {
#pragma unroll
      for (int J = 0; J < 16; ++J) {
        union { unsigned long long qq[2]; bf16x8 v; } ua;
        ua.qq[0] = hq[2*J]; ua.qq[1] = hq[2*J+1];
        int kb = J * 32;
        bf16x8 bh = *reinterpret_cast<const bf16x8*>(bh_ + DIN + kb);
        bf16x8 bl = *reinterpret_cast<const bf16x8*>(bl_ + DIN + kb);
        if (J < 8) { accA = MFMA(ua.v, bh, accA); accA = MFMA(ua.v, bl, accA); }
        else       { accB = MFMA(ua.v, bh, accB); accB = MFMA(ua.v, bl, accB); }
      }
    }

    // stage gates — strictly intra-wave (wave w writes/reads rows 16w..16w+15)
#pragma unroll
    for (int r = 0; r < 4; ++r) {
      int grow = r0 + (lane >> 4) * 4 + r;
      gateS[grow * GST + colA] = accA[r] + accB[r];
    }

    // ---- cell phase: lanes 0..15 of every wave, one batch row each ----
    if (lane < 16) {
      const float keep = 1.0f - (float)rstv;
      const float* g = &gateS[crow * GST];
      float hv[4];
      unsigned short vh[4];
#pragma unroll
      for (int uu = 0; uu < 4; ++uu) {
        float gi = g[uu]      + biasS[uu];
        float gg = g[4 + uu]  + biasS[4 + uu];
        float gf = g[8 + uu]  + biasS[8 + uu] + 1.0f;   // Haiku forget bias
        float go = g[12 + uu] + biasS[12 + uu];
        float iv = sigm(gi), gv = tanhf(gg), fv = sigm(gf), ov = sigm(go);
        float cn = fv * cReg[uu] + iv * gv;
        float hn = ov * tanhf(cn);
        hv[uu] = hn;
        cReg[uu] = cn * keep;
        vh[uu] = f2bf(hn * keep);
      }
      oStash = (f32x4){hv[0], hv[1], hv[2], hv[3]};
      if (t + 1 < TSTEPS) {
        unsigned long long qh = (unsigned long long)vh[0] | ((unsigned long long)vh[1] << 16)
                              | ((unsigned long long)vh[2] << 32) | ((unsigned long long)vh[3] << 48);
        ASTU64(hb + (size_t)((t + 1) & 1) * 8192 + (size_t)crow * 128 + wg, qh);
      }
    }

    if (t + 1 < TSTEPS) {
      // ---- release: data at coherent point, then per-wave flag ----
      asm volatile("s_waitcnt vmcnt(0)" ::: "memory");
      if (lane == 0)
        ASTU32(flags + ((unsigned)wg * 4 + wave) * 16, (unsigned)(t + 1));

      // off-path tail: out store + rst prefetch (under other waves' arrivals)
      if (lane < 16)
        *reinterpret_cast<f32x4*>(out + ((size_t)t * BATCH + crow) * HID + j0) = oStash;
      rstv = (lane < 16 && t + 2 < TSTEPS) ? rst[(t + 2) * BATCH + crow] : 0;

      // ---- acquire: poll this row-block's 128 producer flags (2/lane) ----
      {
        const unsigned tgt = (unsigned)(t + 1);
        const unsigned* fA = flags + ((unsigned)lane * 4 + wave) * 16;
        const unsigned* fB = flags + ((unsigned)(lane + 64) * 4 + wave) * 16;
        while (!__all(ALDU32(fA) >= tgt && ALDU32(fB) >= tgt)) {}
      }
      asm volatile("" ::: "memory");         // no hoisting h loads above acquire

      // ---- issue h(t+1) loads; XPART overlaps their flight ----
      {
        const int rb2 = ((t + 1) & 1) * 8192 + arow * 128 + (klo >> 2);
#pragma unroll
        for (int J = 0; J < 16; ++J) {
          hq[2*J]   = ALDU64(hb + rb2 + J*8);
          hq[2*J+1] = ALDU64(hb + rb2 + J*8 + 1);
        }
      }
      __builtin_amdgcn_sched_barrier(0);     // pin issue point (no sinking)
      accx = (f32x4){0.f, 0.f, 0.f, 0.f};
      XPART(t + 1, accx);
      // keep-alive: force all 32 values materialized here (waitcnt after XPART)
      asm volatile("" :: "v"(hq[0]), "v"(hq[1]), "v"(hq[2]), "v"(hq[3]),
                         "v"(hq[4]), "v"(hq[5]), "v"(hq[6]), "v"(hq[7]));
      asm volatile("" :: "v"(hq[8]), "v"(hq[9]), "v"(hq[10]), "v"(hq[11]),
                         "v"(hq[12]), "v"(hq[13]), "v"(hq[14]), "v"(hq[15]));
      asm volatile("" :: "v"(hq[16]), "v"(hq[17]), "v"(hq[18]), "v"(hq[19]),
                         "v"(hq[20]), "v"(hq[21]), "v"(hq[22]), "v"(hq[23]));
      asm volatile("" :: "v"(hq[24]), "v"(hq[25]), "v"(hq[26]), "v"(hq[27]),
                         "v"(hq[28]), "v"(hq[29]), "v"(hq[30]), "v"(hq[31]));
      __builtin_amdgcn_sched_barrier(0);
    } else {
      if (lane < 16)
        *reinterpret_cast<f32x4*>(out + ((size_t)t * BATCH + crow) * HID + j0) = oStash;
    }
  }
#undef XPART
}

extern "C" void kernel_launch(void* const* d_in, const int* in_sizes, int n_in,
                              void* d_out, int out_size, void* d_ws, size_t ws_size,
                              hipStream_t stream) {
  const float* x   = (const float*)d_in[0];
  const int*   rst = (const int*)d_in[1];
  const float* W   = (const float*)d_in[2];
  const float* b   = (const float*)d_in[3];
  float* out = (float*)d_out;
  char* ws = (char*)d_ws;

  // ws layout (bytes): flags(32K) | hb(128K) | xhi(16M) | xlo(16M)
  unsigned*           flags = (unsigned*)(ws + 0);
  unsigned long long* hb    = (unsigned long long*)(ws + 32768);
  unsigned short*     xhi   = (unsigned short*)(ws + 32768 + 131072);
  unsigned short*     xlo   = (unsigned short*)(ws + 32768 + 131072 + 16777216);

  hipMemsetAsync(ws, 0, 32768, stream);  // flags only (t=0 skips h)

  int n4 = TSTEPS * BATCH * DIN / 4;
  hipLaunchKernelGGL(split_x_kernel, dim3(n4 / 256), dim3(256), 0, stream,
                     x, xhi, xlo, n4);

  void* args[] = {(void*)&xhi, (void*)&xlo, (void*)&rst, (void*)&W, (void*)&b,
                  (void*)&out, (void*)&hb, (void*)&flags};
  hipLaunchCooperativeKernel((void*)lstm_persistent, dim3(NWG), dim3(NTHR),
                             args, 0, stream);
}

// Round 8
// 3138.420 us; speedup vs baseline: 1.6532x; 1.6532x over previous
//
#include <hip/hip_runtime.h>
#include <hip/hip_cooperative_groups.h>

namespace cg = cooperative_groups;

#define TSTEPS 512
#define BATCH  64
#define DIN    256
#define HID    512
#define NWG    128
#define UPW    4            // hidden units per workgroup
#define NTHR   256
#define GST    17           // gate staging stride (floats)
#define WXST   280          // Wx LDS stride (f16): 16B-aligned, 2-way bank max
#define WHST   520          // Wh LDS stride (f16): 16B-aligned, 2-way bank max

typedef __attribute__((ext_vector_type(8))) _Float16 f16x8;
typedef __attribute__((ext_vector_type(4))) _Float16 f16x4;
typedef __attribute__((ext_vector_type(4))) float f32x4;

#define MFMA16(A,B,C) __builtin_amdgcn_mfma_f32_16x16x32_f16(A,B,C,0,0,0)
#define ALDU64(p) __hip_atomic_load(const_cast<unsigned long long*>(p), __ATOMIC_RELAXED, __HIP_MEMORY_SCOPE_AGENT)
#define ALDU32(p) __hip_atomic_load(const_cast<unsigned*>(p), __ATOMIC_RELAXED, __HIP_MEMORY_SCOPE_AGENT)
#define ASTU64(p,v) __hip_atomic_store((p), (v), __ATOMIC_RELAXED, __HIP_MEMORY_SCOPE_AGENT)
#define ASTU32(p,v) __hip_atomic_store((p), (v), __ATOMIC_RELAXED, __HIP_MEMORY_SCOPE_AGENT)

__device__ __forceinline__ float sigm(float x) { return 1.0f / (1.0f + __expf(-x)); }

// one-time: x fp32 -> f16 plane
__global__ void conv_x(const float* __restrict__ x, _Float16* __restrict__ xh, int n4) {
  int i = blockIdx.x * 256 + threadIdx.x;
  if (i >= n4) return;
  float4 v = reinterpret_cast<const float4*>(x)[i];
  f16x4 o;
  o[0] = (_Float16)v.x; o[1] = (_Float16)v.y; o[2] = (_Float16)v.z; o[3] = (_Float16)v.w;
  *reinterpret_cast<f16x4*>(xh + (size_t)i * 4) = o;
}

// one-time: W -> per-WG transposed f16 slices
// WxT: [128 wg][16 c][256 k], WhT: [128 wg][16 c][512 k]; gcol=(c>>2)*512+wg*4+(c&3)
__global__ void w_prep(const float* __restrict__ W,
                       _Float16* __restrict__ WxT, _Float16* __restrict__ WhT) {
  int idx = blockIdx.x * 256 + threadIdx.x;
  if (idx < 128 * 16 * 256) {
    int k = idx & 255, c = (idx >> 8) & 15, wg = idx >> 12;
    int gcol = (c >> 2) * 512 + wg * 4 + (c & 3);
    WxT[idx] = (_Float16)W[k * 2048 + gcol];
  } else if (idx < 128 * 16 * 256 + 128 * 16 * 512) {
    int j = idx - 128 * 16 * 256;
    int k = j & 511, c = (j >> 9) & 15, wg = j >> 13;
    int gcol = (c >> 2) * 512 + wg * 4 + (c & 3);
    WhT[j] = (_Float16)W[(256 + k) * 2048 + gcol];
  }
}

__global__ void __launch_bounds__(NTHR, 1)
lstm_persistent(const _Float16* __restrict__ xh,
                const int* __restrict__ rst,
                const float* __restrict__ bias,
                float* __restrict__ out,
                unsigned long long* __restrict__ hb,   // [2][64][128] u64 (4 f16)
                unsigned* __restrict__ flags,          // [NWG] u32, 64B stride
                const _Float16* __restrict__ WxT,
                const _Float16* __restrict__ WhT) {
  __shared__ _Float16 WxS[16 * WXST];
  __shared__ _Float16 WhS[16 * WHST];
  __shared__ float gateS[BATCH * GST];
  __shared__ unsigned short hstage[4][64];
  __shared__ float biasS[16];

  const int tid = threadIdx.x, wg = blockIdx.x, j0 = wg * UPW;

  // ---- prologue: per-WG W slices -> LDS (vectorized), bias ----
  for (int i = tid; i < 16 * 32; i += NTHR) {
    int c = i >> 5, k8 = (i & 31) * 8;
    *reinterpret_cast<f16x8*>(&WxS[c * WXST + k8]) =
        *reinterpret_cast<const f16x8*>(&WxT[wg * 4096 + c * 256 + k8]);
  }
  for (int i = tid; i < 16 * 64; i += NTHR) {
    int c = i >> 6, k8 = (i & 63) * 8;
    *reinterpret_cast<f16x8*>(&WhS[c * WHST + k8]) =
        *reinterpret_cast<const f16x8*>(&WhT[wg * 8192 + c * 512 + k8]);
  }
  if (tid < 16) biasS[tid] = bias[(tid >> 2) * HID + j0 + (tid & 3)];
  __syncthreads();
  cg::this_grid().sync();                      // once; proven launch config

  // ---- geometry (proven) ----
  const int lane = tid & 63, wave = tid >> 6;
  const int r0   = wave * 16;
  const int arow = r0 + (lane & 15);
  const int klo  = (lane >> 4) * 8;
  const int colA = lane & 15;
  // cell identity: one (row, unit) pair per lane
  const int crow = r0 + (lane >> 2);
  const int cu   = lane & 3;

#define XCHUNK(TT, KC, A) do {                                                   \
    f16x8 ah = *reinterpret_cast<const f16x8*>(                                  \
        xh + ((size_t)(TT) * BATCH + arow) * DIN + (KC) * 32 + klo);             \
    f16x8 bw = *reinterpret_cast<const f16x8*>(&WxS[colA * WXST + (KC) * 32 + klo]); \
    A = MFMA16(ah, bw, A);                                                       \
  } while (0)

  f32x4 accx = {0.f, 0.f, 0.f, 0.f};
#pragma unroll
  for (int kc = 0; kc < 8; ++kc) XCHUNK(0, kc, accx);
  int rstv = rst[BATCH + crow];                // rst[(t=0)+1]
  float oStash = 0.0f, cReg = 0.0f;
  unsigned long long hq[32];

  for (int t = 0; t < TSTEPS; ++t) {
    f32x4 acc = accx;

    // ---- consume h(t): loaded at end of previous iteration ----
    if (t) {
#pragma unroll
      for (int J = 0; J < 16; ++J) {
        union { unsigned long long q[2]; f16x8 v; } ua;
        ua.q[0] = hq[2 * J]; ua.q[1] = hq[2 * J + 1];
        f16x8 bw = *reinterpret_cast<const f16x8*>(&WhS[colA * WHST + J * 32 + klo]);
        acc = MFMA16(ua.v, bw, acc);
      }
    }

    // stage gates — intra-wave only (wave w covers rows r0..r0+15)
#pragma unroll
    for (int r = 0; r < 4; ++r) {
      int grow = r0 + (lane >> 4) * 4 + r;
      gateS[grow * GST + colA] = acc[r];
    }

    // ---- cell: all 64 lanes, one (row, unit) each ----
    {
      const float keep = 1.0f - (float)rstv;
      const float* g = &gateS[crow * GST];
      float gi = g[cu]      + biasS[cu];
      float gg = g[4 + cu]  + biasS[4 + cu];
      float gf = g[8 + cu]  + biasS[8 + cu] + 1.0f;   // Haiku forget bias
      float go = g[12 + cu] + biasS[12 + cu];
      float iv = sigm(gi), gv = tanhf(gg), fv = sigm(gf), ov = sigm(go);
      float cn = fv * cReg + iv * gv;
      float hn = ov * tanhf(cn);
      oStash = hn;
      cReg = cn * keep;
      union { _Float16 f; unsigned short u; } cv;
      cv.f = (_Float16)(hn * keep);
      hstage[wave][lane] = cv.u;                      // [row][unit] packing
    }

    // lanes<16: one u64 h-store per row (agent atomic -> coherent point)
    if (lane < 16 && t + 1 < TSTEPS) {
      int row = r0 + lane;
      ushort4 hs = *reinterpret_cast<ushort4*>(&hstage[wave][lane * 4]);
      unsigned long long q = (unsigned long long)hs.x | ((unsigned long long)hs.y << 16)
                           | ((unsigned long long)hs.z << 32) | ((unsigned long long)hs.w << 48);
      ASTU64(hb + (size_t)((t + 1) & 1) * 8192 + (size_t)row * 128 + wg, q);
    }

    // ---- release: concurrent drain (syncthreads emits vmcnt(0)) + 1 flag/WG ----
    __syncthreads();
    if (t + 1 < TSTEPS) {
      if (tid == 0) ASTU32(flags + wg * 16, (unsigned)(t + 1));

      // off-path: out store, rst prefetch, x-part chunks 0..3 (hide flag RT)
      out[((size_t)t * BATCH + crow) * HID + j0 + cu] = oStash;
      rstv = (t + 2 < TSTEPS) ? rst[(t + 2) * BATCH + crow] : 0;
      accx = (f32x4){0.f, 0.f, 0.f, 0.f};
      XCHUNK(t + 1, 0, accx); XCHUNK(t + 1, 1, accx);
      XCHUNK(t + 1, 2, accx); XCHUNK(t + 1, 3, accx);

      // ---- acquire: 128 pollers, 1 flag each; barrier releases the WG ----
      if (tid < NWG) {
        const unsigned tgt = (unsigned)(t + 1);
        while (ALDU32(flags + tid * 16) < tgt) __builtin_amdgcn_s_sleep(1);
      }
      __syncthreads();
      asm volatile("" ::: "memory");

      // ---- issue h(t+1) loads; x-part chunks 4..7 cover the flight ----
      {
        const int rb2 = ((t + 1) & 1) * 8192 + arow * 128 + (klo >> 2);
#pragma unroll
        for (int J = 0; J < 16; ++J) {
          hq[2 * J]     = ALDU64(hb + rb2 + J * 8);
          hq[2 * J + 1] = ALDU64(hb + rb2 + J * 8 + 1);
        }
      }
      __builtin_amdgcn_sched_barrier(0);       // pin issue point
      XCHUNK(t + 1, 4, accx); XCHUNK(t + 1, 5, accx);
      XCHUNK(t + 1, 6, accx); XCHUNK(t + 1, 7, accx);
      __builtin_amdgcn_sched_barrier(0);
    } else {
      out[((size_t)t * BATCH + crow) * HID + j0 + cu] = oStash;
    }
  }
#undef XCHUNK
}

extern "C" void kernel_launch(void* const* d_in, const int* in_sizes, int n_in,
                              void* d_out, int out_size, void* d_ws, size_t ws_size,
                              hipStream_t stream) {
  const float* x   = (const float*)d_in[0];
  const int*   rst = (const int*)d_in[1];
  const float* W   = (const float*)d_in[2];
  const float* b   = (const float*)d_in[3];
  float* out = (float*)d_out;
  char* ws = (char*)d_ws;

  // ws layout (bytes): flags(32K) | hb(128K) | xh(16M) | WxT(1M) | WhT(2M)
  unsigned*           flags = (unsigned*)(ws + 0);
  unsigned long long* hb    = (unsigned long long*)(ws + 32768);
  _Float16*           xh    = (_Float16*)(ws + 163840);
  _Float16*           WxT   = (_Float16*)(ws + 163840 + 16777216);
  _Float16*           WhT   = (_Float16*)(ws + 163840 + 16777216 + 1048576);

  hipMemsetAsync(ws, 0, 32768, stream);        // flags only (t=0 skips h)

  int n4 = TSTEPS * BATCH * DIN / 4;           // 2,097,152
  hipLaunchKernelGGL(conv_x, dim3(n4 / 256), dim3(256), 0, stream, x, xh, n4);
  hipLaunchKernelGGL(w_prep, dim3(6144), dim3(256), 0, stream, W, WxT, WhT);

  void* args[] = {(void*)&xh, (void*)&rst, (void*)&b, (void*)&out,
                  (void*)&hb, (void*)&flags, (void*)&WxT, (void*)&WhT};
  hipLaunchCooperativeKernel((void*)lstm_persistent, dim3(NWG), dim3(NTHR),
                             args, 0, stream);
}

// Round 10
// 2968.126 us; speedup vs baseline: 1.7480x; 1.0574x over previous
//
#include <hip/hip_runtime.h>

#define TSTEPS 512
#define BATCH  64
#define DIN    256
#define HID    512
#define NWG    128
#define NTHR   256
#define VR     512          // virtual rows = 64 batch x 8 chunks
#define NCH    8            // chunks per row
#define GST    16           // gateS stride (floats)
#define WXST   280          // Wx LDS stride (f16)
#define WHST   520          // Wh LDS stride (f16)

typedef __attribute__((ext_vector_type(8))) _Float16 f16x8;
typedef __attribute__((ext_vector_type(4))) _Float16 f16x4;
typedef __attribute__((ext_vector_type(4))) float f32x4;

#define MFMA16(A,B,C) __builtin_amdgcn_mfma_f32_16x16x32_f16(A,B,C,0,0,0)
#define ALDU64(p) __hip_atomic_load(const_cast<unsigned long long*>(p), __ATOMIC_RELAXED, __HIP_MEMORY_SCOPE_AGENT)
#define ALDU32(p) __hip_atomic_load(const_cast<unsigned*>(p), __ATOMIC_RELAXED, __HIP_MEMORY_SCOPE_AGENT)
#define ASTU64(p,v) __hip_atomic_store((p), (v), __ATOMIC_RELAXED, __HIP_MEMORY_SCOPE_AGENT)
#define ASTU32(p,v) __hip_atomic_store((p), (v), __ATOMIC_RELAXED, __HIP_MEMORY_SCOPE_AGENT)

__device__ __forceinline__ float sigm(float x) { return 1.0f / (1.0f + __expf(-x)); }

// one-time: x fp32 -> f16 plane (R8-proven)
__global__ void conv_x(const float* __restrict__ x, _Float16* __restrict__ xh, int n4) {
  int i = blockIdx.x * 256 + threadIdx.x;
  if (i >= n4) return;
  float4 v = reinterpret_cast<const float4*>(x)[i];
  f16x4 o;
  o[0] = (_Float16)v.x; o[1] = (_Float16)v.y; o[2] = (_Float16)v.z; o[3] = (_Float16)v.w;
  *reinterpret_cast<f16x4*>(xh + (size_t)i * 4) = o;
}

// one-time: W -> per-WG transposed f16 slices. col c = unit*4 + gate:
// gcol = gate*512 + wg*4 + unit  (cell reads {i,g,f,o} of one unit as f32x4)
__global__ void w_prep(const float* __restrict__ W,
                       _Float16* __restrict__ WxT, _Float16* __restrict__ WhT) {
  int idx = blockIdx.x * 256 + threadIdx.x;
  if (idx < 128 * 16 * 256) {
    int k = idx & 255, c = (idx >> 8) & 15, wg = idx >> 12;
    int gcol = (c & 3) * 512 + wg * 4 + (c >> 2);
    WxT[idx] = (_Float16)W[k * 2048 + gcol];
  } else if (idx < 128 * 16 * 256 + 128 * 16 * 512) {
    int j = idx - 128 * 16 * 256;
    int k = j & 511, c = (j >> 9) & 15, wg = j >> 13;
    int gcol = (c & 3) * 512 + wg * 4 + (c >> 2);
    WhT[j] = (_Float16)W[(256 + k) * 2048 + gcol];
  }
}

// segmentation: cut each batch row at first reset >= c*64 (monotone-clamped).
// vr = c*64 + b. Outputs tS[vr] (real start t), segLen[vr], maxLen.
__global__ void seg_prep(const int* __restrict__ rst, int* __restrict__ tS,
                         int* __restrict__ segLen, int* __restrict__ maxLen) {
  __shared__ int redu[64];
  const int b = threadIdx.x;                  // 64 threads, 1 block
  int cut[NCH + 1];
  cut[0] = 0; cut[NCH] = TSTEPS;
  for (int c = 1; c < NCH; ++c) {
    int t = c * 64;
    while (t < TSTEPS && rst[t * BATCH + b] == 0) ++t;
    cut[c] = t;
  }
  for (int c = 1; c < NCH; ++c) if (cut[c] < cut[c - 1]) cut[c] = cut[c - 1];
  int mymax = 0;
  for (int c = 0; c < NCH; ++c) {
    int vr = c * 64 + b;
    tS[vr] = cut[c];
    int L = cut[c + 1] - cut[c];
    segLen[vr] = L;
    if (L > mymax) mymax = L;
  }
  redu[b] = mymax;
  __syncthreads();
  for (int s = 32; s > 0; s >>= 1) {
    if (b < s && redu[b + s] > redu[b]) redu[b] = redu[b + s];
    __syncthreads();
  }
  if (b == 0) *maxLen = redu[0];
}

// REGULAR launch (no cooperative): 128 blocks <= 256 CUs, each schedulable
// (62.5 KB LDS < 160 KB/CU, <=512 VGPR) => all co-resident; cross-WG sync via
// proven agent-scope atomic flag protocol. No grid.sync needed: the k=0 flag
// poll already orders "all WGs stored h" before any h read.
__global__ void __launch_bounds__(NTHR, 1)
lstm_persistent(const _Float16* __restrict__ xh,
                const int* __restrict__ rst,
                const float* __restrict__ bias,
                float* __restrict__ out,
                unsigned long long* __restrict__ hb,   // [2][VR][128] u64 (4 f16)
                unsigned* __restrict__ flags,          // [NWG] u32, 64B stride
                const _Float16* __restrict__ WxT,
                const _Float16* __restrict__ WhT,
                const int* __restrict__ tS,
                const int* __restrict__ segLen,
                const int* __restrict__ maxLenPtr) {
  // LDS: 8960 + 16640 + 32768 + 4096 + 64 = 62528 B
  __shared__ _Float16 WxS[16 * WXST];
  __shared__ _Float16 WhS[16 * WHST];
  __shared__ float gateS[VR * GST];
  __shared__ unsigned short hstage[VR * 4];
  __shared__ float biasS[16];

  const int tid = threadIdx.x, wg = blockIdx.x;

  // ---- prologue: W slices -> LDS, bias ----
  for (int i = tid; i < 16 * 32; i += NTHR) {
    int c = i >> 5, k8 = (i & 31) * 8;
    *reinterpret_cast<f16x8*>(&WxS[c * WXST + k8]) =
        *reinterpret_cast<const f16x8*>(&WxT[wg * 4096 + c * 256 + k8]);
  }
  for (int i = tid; i < 16 * 64; i += NTHR) {
    int c = i >> 6, k8 = (i & 63) * 8;
    *reinterpret_cast<f16x8*>(&WhS[c * WHST + k8]) =
        *reinterpret_cast<const f16x8*>(&WhT[wg * 8192 + c * 512 + k8]);
  }
  if (tid < 16) biasS[tid] = bias[(tid & 3) * HID + wg * 4 + (tid >> 2)];
  __syncthreads();

  const int ML = maxLenPtr[0];

  // ---- geometry ----
  const int lane = tid & 63, wave = tid >> 6;
  const int colA = lane & 15, klo = (lane >> 4) * 8;
  const int rbase = wave * 128;              // this wave's 128 virtual rows
  const int q = lane >> 2, cu = lane & 3;    // cell: unit cu for rows rbase+q+16m

  int tSr[8];                                // MFMA-side start times per tile
#pragma unroll
  for (int r = 0; r < 8; ++r) tSr[r] = tS[rbase + r * 16 + colA];
  int tSc[8], lenc[8];                       // cell-side per m
#pragma unroll
  for (int m = 0; m < 8; ++m) {
    int row = rbase + q + 16 * m;
    tSc[m] = tS[row];
    lenc[m] = segLen[row];
  }
  const f32x4 biasV = *reinterpret_cast<const f32x4*>(&biasS[cu * 4]);

  float cReg[8], keep[8], hv[8];
#pragma unroll
  for (int m = 0; m < 8; ++m) {
    cReg[m] = 0.0f;
    int row = rbase + q + 16 * m, b_ = row & 63;
    keep[m] = (1 < lenc[m]) ? 1.0f - (float)rst[(tSc[m] + 1) * BATCH + b_] : 0.0f;
  }

#define XPART_TILE(R, TT) do {                                                   \
    int t_ = tSr[R] + (TT); if (t_ > TSTEPS - 1) t_ = TSTEPS - 1;                \
    const int b_ = ((R & 3) * 16 + colA) & 63;                                   \
    const _Float16* xr_ = xh + ((size_t)t_ * BATCH + b_) * DIN + klo;            \
    _Pragma("unroll")                                                            \
    for (int c2 = 0; c2 < 8; ++c2) {                                             \
      f16x8 av = *reinterpret_cast<const f16x8*>(xr_ + c2 * 32);                 \
      f16x8 bw = *reinterpret_cast<const f16x8*>(&WxS[colA * WXST + c2 * 32 + klo]); \
      acc[R] = MFMA16(av, bw, acc[R]);                                           \
    }                                                                            \
  } while (0)

#define HCONSUME(R, HQ) do {                                                     \
    _Pragma("unroll")                                                            \
    for (int J = 0; J < 16; ++J) {                                               \
      union { unsigned long long qq[2]; f16x8 v; } ua;                           \
      ua.qq[0] = HQ[2 * J]; ua.qq[1] = HQ[2 * J + 1];                            \
      f16x8 bw = *reinterpret_cast<const f16x8*>(&WhS[colA * WHST + J * 32 + klo]); \
      acc[R] = MFMA16(ua.v, bw, acc[R]);                                         \
    }                                                                            \
    _Pragma("unroll")                                                            \
    for (int rr = 0; rr < 4; ++rr) {                                             \
      int grow = rbase + (R) * 16 + (lane >> 4) * 4 + rr;                        \
      gateS[grow * GST + colA] = acc[R][rr];                                     \
    }                                                                            \
  } while (0)

#define HISSUE(R, HQ, PAR) do {                                                  \
    const size_t rb_ = (size_t)(PAR) * 65536                                     \
        + (size_t)(rbase + (R) * 16 + colA) * 128 + (klo >> 2);                  \
    _Pragma("unroll")                                                            \
    for (int J = 0; J < 16; ++J) {                                               \
      HQ[2 * J]     = ALDU64(hb + rb_ + J * 8);                                  \
      HQ[2 * J + 1] = ALDU64(hb + rb_ + J * 8 + 1);                              \
    }                                                                            \
    __builtin_amdgcn_sched_barrier(0);                                           \
  } while (0)

  f32x4 acc[8];
#pragma unroll
  for (int r = 0; r < 8; ++r) acc[r] = (f32x4){0.f, 0.f, 0.f, 0.f};
  XPART_TILE(0, 0); XPART_TILE(1, 0); XPART_TILE(2, 0); XPART_TILE(3, 0);
  XPART_TILE(4, 0); XPART_TILE(5, 0); XPART_TILE(6, 0); XPART_TILE(7, 0);

  unsigned long long hqA[32], hqB[32];

  for (int k = 0; k < ML; ++k) {
    const int par = k & 1;

    if (k) {
      // consume 8 tiles, 2-deep pipelined re-issue (tile r+2 into freed buffer)
      HCONSUME(0, hqA); HISSUE(2, hqA, par);
      HCONSUME(1, hqB); HISSUE(3, hqB, par);
      HCONSUME(2, hqA); HISSUE(4, hqA, par);
      HCONSUME(3, hqB); HISSUE(5, hqB, par);
      HCONSUME(4, hqA); HISSUE(6, hqA, par);
      HCONSUME(5, hqB); HISSUE(7, hqB, par);
      HCONSUME(6, hqA);
      HCONSUME(7, hqB);
    } else {
#pragma unroll
      for (int r = 0; r < 8; ++r) {
#pragma unroll
        for (int rr = 0; rr < 4; ++rr) {
          int grow = rbase + r * 16 + (lane >> 4) * 4 + rr;
          gateS[grow * GST + colA] = acc[r][rr];
        }
      }
    }
    __syncthreads();                         // gateS ready

    // ---- cell: 8 (row, unit) per thread ----
#pragma unroll
    for (int m = 0; m < 8; ++m) {
      const int row = rbase + q + 16 * m;
      f32x4 g4 = *reinterpret_cast<const f32x4*>(&gateS[row * GST + cu * 4]);
      float gi = g4[0] + biasV[0];
      float gg = g4[1] + biasV[1];
      float gf = g4[2] + biasV[2] + 1.0f;    // Haiku forget bias
      float go = g4[3] + biasV[3];
      float iv = sigm(gi), gv = tanhf(gg), fv = sigm(gf), ov = sigm(go);
      float cn = fv * cReg[m] + iv * gv;
      float hn = ov * tanhf(cn);
      hv[m] = hn;
      cReg[m] = cn * keep[m];
      union { _Float16 f; unsigned short u; } cvt;
      cvt.f = (_Float16)(hn * keep[m]);
      hstage[row * 4 + cu] = cvt.u;
    }
    __syncthreads();                         // hstage ready

    if (k + 1 < ML) {
      // ---- h-line stores: 2 per thread ----
      {
        const size_t wb = (size_t)((k + 1) & 1) * 65536;
        int r1 = tid, r2 = tid + 256;
        unsigned long long q1 = *reinterpret_cast<unsigned long long*>(&hstage[r1 * 4]);
        unsigned long long q2 = *reinterpret_cast<unsigned long long*>(&hstage[r2 * 4]);
        ASTU64(hb + wb + (size_t)r1 * 128 + wg, q1);
        ASTU64(hb + wb + (size_t)r2 * 128 + wg, q2);
      }
      __syncthreads();                       // drain (vmcnt(0) before barrier)
      if (tid == 0) ASTU32(flags + wg * 16, (unsigned)(k + 1));

      // ---- off-path tail: out stores, keep gather, x tiles 0..3 ----
#pragma unroll
      for (int m = 0; m < 8; ++m) {
        if (k < lenc[m]) {
          const int row = rbase + q + 16 * m, b_ = row & 63;
          out[((size_t)(tSc[m] + k) * BATCH + b_) * HID + wg * 4 + cu] = hv[m];
        }
      }
#pragma unroll
      for (int m = 0; m < 8; ++m) {
        const int row = rbase + q + 16 * m, b_ = row & 63;
        keep[m] = (k + 2 < lenc[m]) ? 1.0f - (float)rst[(tSc[m] + k + 2) * BATCH + b_] : 0.0f;
      }
      acc[0] = (f32x4){0.f,0.f,0.f,0.f}; acc[1] = (f32x4){0.f,0.f,0.f,0.f};
      acc[2] = (f32x4){0.f,0.f,0.f,0.f}; acc[3] = (f32x4){0.f,0.f,0.f,0.f};
      XPART_TILE(0, k + 1); XPART_TILE(1, k + 1);
      XPART_TILE(2, k + 1); XPART_TILE(3, k + 1);

      // ---- acquire: 128 pollers + barrier ----
      if (tid < NWG) {
        const unsigned tgt = (unsigned)(k + 1);
        while (ALDU32(flags + tid * 16) < tgt) __builtin_amdgcn_s_sleep(1);
      }
      __syncthreads();
      asm volatile("" ::: "memory");

      // ---- issue h tiles 0,1 for k+1; x tiles 4..7 cover the flight ----
      HISSUE(0, hqA, (k + 1) & 1);
      HISSUE(1, hqB, (k + 1) & 1);
      acc[4] = (f32x4){0.f,0.f,0.f,0.f}; acc[5] = (f32x4){0.f,0.f,0.f,0.f};
      acc[6] = (f32x4){0.f,0.f,0.f,0.f}; acc[7] = (f32x4){0.f,0.f,0.f,0.f};
      XPART_TILE(4, k + 1); XPART_TILE(5, k + 1);
      XPART_TILE(6, k + 1); XPART_TILE(7, k + 1);
      __builtin_amdgcn_sched_barrier(0);
    } else {
#pragma unroll
      for (int m = 0; m < 8; ++m) {
        if (k < lenc[m]) {
          const int row = rbase + q + 16 * m, b_ = row & 63;
          out[((size_t)(tSc[m] + k) * BATCH + b_) * HID + wg * 4 + cu] = hv[m];
        }
      }
    }
  }
#undef XPART_TILE
#undef HCONSUME
#undef HISSUE
}

extern "C" void kernel_launch(void* const* d_in, const int* in_sizes, int n_in,
                              void* d_out, int out_size, void* d_ws, size_t ws_size,
                              hipStream_t stream) {
  const float* x   = (const float*)d_in[0];
  const int*   rst = (const int*)d_in[1];
  const float* W   = (const float*)d_in[2];
  const float* b   = (const float*)d_in[3];
  float* out = (float*)d_out;
  char* ws = (char*)d_ws;

  // ws: flags(8K) | tS(2K) | segLen(2K) | maxLen(pad->16K) | hb(1M) | xh(16M) | WxT(1M) | WhT(2M)
  unsigned*           flags  = (unsigned*)(ws + 0);
  int*                tSp    = (int*)(ws + 8192);
  int*                segLen = (int*)(ws + 10240);
  int*                maxLen = (int*)(ws + 12288);
  unsigned long long* hb     = (unsigned long long*)(ws + 16384);
  _Float16*           xh     = (_Float16*)(ws + 16384 + 1048576);
  _Float16*           WxT    = (_Float16*)(ws + 16384 + 1048576 + 16777216);
  _Float16*           WhT    = (_Float16*)(ws + 16384 + 1048576 + 16777216 + 1048576);

  hipMemsetAsync(ws, 0, 16384, stream);      // flags + seg arrays region

  int n4 = TSTEPS * BATCH * DIN / 4;
  hipLaunchKernelGGL(conv_x, dim3(n4 / 256), dim3(256), 0, stream, x, xh, n4);
  hipLaunchKernelGGL(w_prep, dim3(6144), dim3(256), 0, stream, W, WxT, WhT);
  hipLaunchKernelGGL(seg_prep, dim3(1), dim3(64), 0, stream, rst, tSp, segLen, maxLen);

  // regular launch — no cooperative contract needed (see kernel comment)
  hipLaunchKernelGGL(lstm_persistent, dim3(NWG), dim3(NTHR), 0, stream,
                     xh, rst, b, out, hb, flags, WxT, WhT, tSp, segLen, maxLen);
}

// Round 12
// 563.511 us; speedup vs baseline: 9.2072x; 5.2672x over previous
//
#include <hip/hip_runtime.h>

#define TSTEPS 512
#define BATCH  64
#define DIN    256
#define HID    512
#define NCH    8            // chunks per batch row (segmentation)
#define VR     512          // virtual rows = 64 batch x 8 chunks
#define NRB    16           // row-blocks (32 VRs each)
#define NUB    32           // unit-blocks (16 units = 64 gate-cols each)
#define NWG    512          // NRB * NUB
#define NTHR   256
#define HSST   264          // hS row stride (f16): 256 + 8
#define GST    67           // gateS row stride (f32): odd -> 2-way banks

typedef __attribute__((ext_vector_type(8))) _Float16 f16x8;
typedef __attribute__((ext_vector_type(4))) _Float16 f16x4;
typedef __attribute__((ext_vector_type(4))) float f32x4;
typedef __attribute__((ext_vector_type(2))) float f32x2;

#define MFMA16(A,B,C) __builtin_amdgcn_mfma_f32_16x16x32_f16(A,B,C,0,0,0)
#define ALDU64(p) __hip_atomic_load(const_cast<unsigned long long*>(p), __ATOMIC_RELAXED, __HIP_MEMORY_SCOPE_AGENT)
#define ALDU32(p) __hip_atomic_load(const_cast<unsigned*>(p), __ATOMIC_RELAXED, __HIP_MEMORY_SCOPE_AGENT)
#define ASTU32(p,v) __hip_atomic_store((p), (v), __ATOMIC_RELAXED, __HIP_MEMORY_SCOPE_AGENT)

__device__ __forceinline__ float sigm(float x) { return 1.0f / (1.0f + __expf(-x)); }

// one-time: x fp32 -> f16 plane (proven)
__global__ void conv_x(const float* __restrict__ x, _Float16* __restrict__ xh, int n4) {
  int i = blockIdx.x * 256 + threadIdx.x;
  if (i >= n4) return;
  float4 v = reinterpret_cast<const float4*>(x)[i];
  f16x4 o;
  o[0] = (_Float16)v.x; o[1] = (_Float16)v.y; o[2] = (_Float16)v.z; o[3] = (_Float16)v.w;
  *reinterpret_cast<f16x4*>(xh + (size_t)i * 4) = o;
}

// one-time: W -> per-unit-block transposed f16. Local col cc = unit*4 + gate
// (unit in [0,16)); global W col = gate*512 + ub*16 + unit.
__global__ void w_prep(const float* __restrict__ W,
                       _Float16* __restrict__ WxT, _Float16* __restrict__ WhT) {
  int idx = blockIdx.x * 256 + threadIdx.x;
  if (idx < NUB * 64 * 256) {
    int k = idx & 255, cc = (idx >> 8) & 63, ub = idx >> 14;
    int unit = cc >> 2, g = cc & 3;
    int gcol = g * HID + ub * 16 + unit;
    WxT[idx] = (_Float16)W[k * 2048 + gcol];
  } else if (idx < NUB * 64 * 256 + NUB * 64 * 512) {
    int j = idx - NUB * 64 * 256;
    int k = j & 511, cc = (j >> 9) & 63, ub = j >> 15;
    int unit = cc >> 2, g = cc & 3;
    int gcol = g * HID + ub * 16 + unit;
    WhT[j] = (_Float16)W[(DIN + k) * 2048 + gcol];
  }
}

// segmentation (proven) + per-row-block max length (block = 32 VRs)
__global__ void seg_prep(const int* __restrict__ rst, int* __restrict__ tS,
                         int* __restrict__ segLen, int* __restrict__ maxLenB) {
  __shared__ int sMax[NRB];
  const int b = threadIdx.x;                  // 64 threads, 1 block
  if (b < NRB) sMax[b] = 0;
  __syncthreads();
  int cut[NCH + 1];
  cut[0] = 0; cut[NCH] = TSTEPS;
  for (int c = 1; c < NCH; ++c) {
    int t = c * 64;
    while (t < TSTEPS && rst[t * BATCH + b] == 0) ++t;
    cut[c] = t;
  }
  for (int c = 1; c < NCH; ++c) if (cut[c] < cut[c - 1]) cut[c] = cut[c - 1];
  for (int c = 0; c < NCH; ++c) {
    int vr = c * 64 + b;
    tS[vr] = cut[c];
    int L = cut[c + 1] - cut[c];
    segLen[vr] = L;
    atomicMax(&sMax[c * 2 + (b >> 5)], L);   // block rb = c*2 + (b>=32)
  }
  __syncthreads();
  if (b < NRB) maxLenB[b] = sMax[b];
}

// 512 WGs (2/CU, all co-resident: 26KB LDS, <=256 VGPR). Per-block dataflow
// sync via agent-atomic flags (proven protocol). h staged once to LDS/WG.
// FIX vs R11: hb row stride = 128 u64 (512 f16 = full h row), was 64.
__global__ void __launch_bounds__(NTHR, 2)
lstm_persistent(const _Float16* __restrict__ xh,
                const int* __restrict__ rst,
                const float* __restrict__ bias,
                float* __restrict__ out,
                unsigned long long* __restrict__ hb,   // [2][VR][128] u64 (f16 h)
                unsigned* __restrict__ flags,          // [NWG][16] u32
                const _Float16* __restrict__ WxT,
                const _Float16* __restrict__ WhT,
                const int* __restrict__ tS,
                const int* __restrict__ segLen,
                const int* __restrict__ maxLenB) {
  __shared__ _Float16 hS[32 * HSST];          // 16.9 KB (one K-group of 32 rows)
  __shared__ float gateS[32 * GST];           // 8.6 KB
  __shared__ float biasS[64];

  const int tid = threadIdx.x, wg = blockIdx.x;
  const int rb = wg >> 5, ub = wg & 31;
  const int vr0 = rb * 32;
  const int lane = tid & 63, wave = tid >> 6;
  const int colA = lane & 15, klo = (lane >> 4) * 8;

  // ---- prologue: W fragments -> registers (wave w owns col-tile w) ----
  f16x8 wx[8], wh[16];
  {
    const _Float16* px = WxT + ((size_t)ub * 64 + wave * 16 + colA) * 256 + klo;
    const _Float16* ph = WhT + ((size_t)ub * 64 + wave * 16 + colA) * 512 + klo;
#pragma unroll
    for (int ch = 0; ch < 8; ++ch) wx[ch] = *(const f16x8*)(px + ch * 32);
#pragma unroll
    for (int ch = 0; ch < 16; ++ch) wh[ch] = *(const f16x8*)(ph + ch * 32);
  }
  if (tid < 64) {
    int unit = tid >> 2, g = tid & 3;
    biasS[tid] = bias[g * HID + ub * 16 + unit];
  }

  // MFMA-side per-lane row start times (rows rt*16+colA of this block)
  int tSr0 = tS[vr0 + colA];
  int tSr1 = tS[vr0 + 16 + colA];

  // cell-side: row crow, units 2p and 2p+1 (intra-wave: p in {2w,2w+1})
  const int crow = tid & 31, p = tid >> 5;
  const int vrc = vr0 + crow, bc = vrc & 63;
  const int tSc_ = tS[vrc], lenc_ = segLen[vrc];
  const int ML = maxLenB[rb];
  float cA = 0.f, cB = 0.f;

  __syncthreads();
  float bA[4], bB[4];
#pragma unroll
  for (int g = 0; g < 4; ++g) { bA[g] = biasS[8 * p + g]; bB[g] = biasS[8 * p + 4 + g]; }

  const int srow = tid >> 3, ss = tid & 7;    // h-staging assignment

  for (int k = 0; k < ML; ++k) {
    // ---- issue x loads BEFORE poll (latency hides under poll+staging) ----
    f16x8 xq0[8], xq1[8];
    {
      int t0 = tSr0 + k; if (t0 > TSTEPS - 1) t0 = TSTEPS - 1;
      int t1 = tSr1 + k; if (t1 > TSTEPS - 1) t1 = TSTEPS - 1;
      const int b0 = (vr0 + colA) & 63, b1 = (vr0 + 16 + colA) & 63;
      const _Float16* x0 = xh + ((size_t)t0 * BATCH + b0) * DIN + klo;
      const _Float16* x1 = xh + ((size_t)t1 * BATCH + b1) * DIN + klo;
#pragma unroll
      for (int ch = 0; ch < 8; ++ch) {
        xq0[ch] = *(const f16x8*)(x0 + ch * 32);
        xq1[ch] = *(const f16x8*)(x1 + ch * 32);
      }
    }
    __builtin_amdgcn_sched_barrier(0);

    if (k) {
      // ---- acquire: poll only MY row-block's 32 producer flags ----
      if (tid < NUB) {
        const unsigned tgt = (unsigned)k;
        while (ALDU32(flags + (rb * NUB + tid) * 16) < tgt) __builtin_amdgcn_s_sleep(1);
      }
      __syncthreads();
      asm volatile("" ::: "memory");
    }

    f32x4 acc0 = {0.f, 0.f, 0.f, 0.f}, acc1 = {0.f, 0.f, 0.f, 0.f};

    if (k) {
      const size_t hbase = (size_t)(k & 1) * (VR * 128) + (size_t)(vr0 + srow) * 128;
      unsigned long long hq[8];
      // group 0 (k-dims 0..255) issue
#pragma unroll
      for (int j = 0; j < 8; ++j) hq[j] = ALDU64(hb + hbase + ss + 8 * j);
      __builtin_amdgcn_sched_barrier(0);
      // x-part under g0 flight (x landed: issued pre-poll)
#pragma unroll
      for (int ch = 0; ch < 8; ++ch) {
        acc0 = MFMA16(xq0[ch], wx[ch], acc0);
        acc1 = MFMA16(xq1[ch], wx[ch], acc1);
      }
#pragma unroll
      for (int j = 0; j < 8; ++j)
        *(unsigned long long*)&hS[srow * HSST + (ss + 8 * j) * 4] = hq[j];
      __syncthreads();
      // group 1 (k-dims 256..511) issue; consume g0 under its flight
#pragma unroll
      for (int j = 0; j < 8; ++j) hq[j] = ALDU64(hb + hbase + 64 + ss + 8 * j);
      __builtin_amdgcn_sched_barrier(0);
#pragma unroll
      for (int ch = 0; ch < 8; ++ch) {
        f16x8 a0 = *(const f16x8*)&hS[colA * HSST + ch * 32 + klo];
        f16x8 a1 = *(const f16x8*)&hS[(16 + colA) * HSST + ch * 32 + klo];
        acc0 = MFMA16(a0, wh[ch], acc0);
        acc1 = MFMA16(a1, wh[ch], acc1);
      }
      __syncthreads();
#pragma unroll
      for (int j = 0; j < 8; ++j)
        *(unsigned long long*)&hS[srow * HSST + (ss + 8 * j) * 4] = hq[j];
      __syncthreads();
#pragma unroll
      for (int ch = 0; ch < 8; ++ch) {
        f16x8 a0 = *(const f16x8*)&hS[colA * HSST + ch * 32 + klo];
        f16x8 a1 = *(const f16x8*)&hS[(16 + colA) * HSST + ch * 32 + klo];
        acc0 = MFMA16(a0, wh[8 + ch], acc0);
        acc1 = MFMA16(a1, wh[8 + ch], acc1);
      }
    } else {
#pragma unroll
      for (int ch = 0; ch < 8; ++ch) {
        acc0 = MFMA16(xq0[ch], wx[ch], acc0);
        acc1 = MFMA16(xq1[ch], wx[ch], acc1);
      }
    }

    // ---- stage gates: wave w writes cols 16w..16w+15 (intra-wave w/ cell) ----
#pragma unroll
    for (int rr = 0; rr < 4; ++rr) {
      int row0 = (lane >> 4) * 4 + rr;
      gateS[row0 * GST + wave * 16 + colA]        = acc0[rr];
      gateS[(16 + row0) * GST + wave * 16 + colA] = acc1[rr];
    }

    // ---- cell: row crow, units 2p & 2p+1 (gateS cols 8p..8p+7, same wave) ----
    {
      int kidx = tSc_ + k + 1; if (kidx > TSTEPS - 1) kidx = TSTEPS - 1;
      float keep = 1.0f - (float)rst[kidx * BATCH + bc];
      const float* g = &gateS[crow * GST + 8 * p];
      float i0 = sigm(g[0] + bA[0]);
      float t0 = tanhf(g[1] + bA[1]);
      float f0 = sigm(g[2] + bA[2] + 1.0f);    // Haiku forget bias
      float o0 = sigm(g[3] + bA[3]);
      float i1 = sigm(g[4] + bB[0]);
      float t1 = tanhf(g[5] + bB[1]);
      float f1 = sigm(g[6] + bB[2] + 1.0f);
      float o1 = sigm(g[7] + bB[3]);
      float cn0 = f0 * cA + i0 * t0, cn1 = f1 * cB + i1 * t1;
      float hn0 = o0 * tanhf(cn0),   hn1 = o1 * tanhf(cn1);
      cA = cn0 * keep; cB = cn1 * keep;
      if (k < lenc_) {
        f32x2 o2 = {hn0, hn1};
        *(f32x2*)&out[((size_t)(tSc_ + k) * BATCH + bc) * HID + ub * 16 + 2 * p] = o2;
      }
      if (k + 1 < ML) {
        union { _Float16 f[2]; unsigned u; } cv;
        cv.f[0] = (_Float16)(hn0 * keep);
        cv.f[1] = (_Float16)(hn1 * keep);
        unsigned* hb32 = (unsigned*)(hb + (size_t)((k + 1) & 1) * (VR * 128) + (size_t)vrc * 128);
        ASTU32(hb32 + ub * 8 + p, cv.u);
      }
    }

    if (k + 1 < ML) {
      __syncthreads();                 // drain: h + out stores at coherent point
      if (tid == 0) ASTU32(flags + wg * 16, (unsigned)(k + 1));
    }
  }
}

extern "C" void kernel_launch(void* const* d_in, const int* in_sizes, int n_in,
                              void* d_out, int out_size, void* d_ws, size_t ws_size,
                              hipStream_t stream) {
  const float* x   = (const float*)d_in[0];
  const int*   rst = (const int*)d_in[1];
  const float* W   = (const float*)d_in[2];
  const float* b   = (const float*)d_in[3];
  float* out = (float*)d_out;
  char* ws = (char*)d_ws;

  // ws: flags(32K) | tS(2K) | segLen(2K) | maxLenB(4K pad) | hb(1M) | xh(16M) | WxT(1M) | WhT(2M)
  unsigned*           flags  = (unsigned*)(ws + 0);
  int*                tSp    = (int*)(ws + 32768);
  int*                segLen = (int*)(ws + 34816);
  int*                maxLenB= (int*)(ws + 36864);
  unsigned long long* hb     = (unsigned long long*)(ws + 40960);
  _Float16*           xh     = (_Float16*)(ws + 40960 + 1048576);
  _Float16*           WxT    = (_Float16*)(ws + 40960 + 1048576 + 16777216);
  _Float16*           WhT    = (_Float16*)(ws + 40960 + 1048576 + 16777216 + 1048576);

  hipMemsetAsync(ws, 0, 32768, stream);      // flags = 0 each launch (replay-safe)

  int n4 = TSTEPS * BATCH * DIN / 4;
  hipLaunchKernelGGL(conv_x, dim3(n4 / 256), dim3(256), 0, stream, x, xh, n4);
  hipLaunchKernelGGL(w_prep, dim3(6144), dim3(256), 0, stream, W, WxT, WhT);
  hipLaunchKernelGGL(seg_prep, dim3(1), dim3(64), 0, stream, rst, tSp, segLen, maxLenB);

  hipLaunchKernelGGL(lstm_persistent, dim3(NWG), dim3(NTHR), 0, stream,
                     xh, rst, b, out, hb, flags, WxT, WhT, tSp, segLen, maxLenB);
}

// Round 13
// 505.703 us; speedup vs baseline: 10.2597x; 1.1143x over previous
//
#include <hip/hip_runtime.h>

#define TSTEPS 512
#define BATCH  64
#define DIN    256
#define HID    512
#define NCH    8            // chunks per batch row (segmentation)
#define VR     512          // virtual rows = 64 batch x 8 chunks
#define NRB    16           // row-blocks (32 VRs each)
#define NUB    32           // unit-blocks (16 units = 64 gate-cols each)
#define NWG    512          // NRB * NUB
#define NTHR   256
#define HSST   520          // hS row stride (f16): 512+8, 16B-aligned, 2-way banks
#define GST    67           // gateS row stride (f32): odd -> 2-way banks

typedef __attribute__((ext_vector_type(8))) _Float16 f16x8;
typedef __attribute__((ext_vector_type(4))) _Float16 f16x4;
typedef __attribute__((ext_vector_type(4))) float f32x4;
typedef __attribute__((ext_vector_type(2))) float f32x2;

#define MFMA16(A,B,C) __builtin_amdgcn_mfma_f32_16x16x32_f16(A,B,C,0,0,0)
#define ALDU32(p) __hip_atomic_load(const_cast<unsigned*>(p), __ATOMIC_RELAXED, __HIP_MEMORY_SCOPE_AGENT)
#define ASTU32(p,v) __hip_atomic_store((p), (v), __ATOMIC_RELAXED, __HIP_MEMORY_SCOPE_AGENT)

__device__ __forceinline__ float sigm(float x) { return 1.0f / (1.0f + __expf(-x)); }

// 16B coherent-point load: bypass L1 (sc0) + L2 (sc1) -> reads LLC-fresh data.
// Producer side wrote via agent atomic stores (write-through to LLC).
__device__ __forceinline__ void gld16_cc(f16x8& d, const void* p) {
  asm volatile("global_load_dwordx4 %0, %1, off sc0 sc1" : "=v"(d) : "v"(p));
}

// one-time: x fp32 -> f16 plane (proven)
__global__ void conv_x(const float* __restrict__ x, _Float16* __restrict__ xh, int n4) {
  int i = blockIdx.x * 256 + threadIdx.x;
  if (i >= n4) return;
  float4 v = reinterpret_cast<const float4*>(x)[i];
  f16x4 o;
  o[0] = (_Float16)v.x; o[1] = (_Float16)v.y; o[2] = (_Float16)v.z; o[3] = (_Float16)v.w;
  *reinterpret_cast<f16x4*>(xh + (size_t)i * 4) = o;
}

// one-time: W -> per-unit-block transposed f16. Local col cc = unit*4 + gate
// (unit in [0,16)); global W col = gate*512 + ub*16 + unit.  (proven)
__global__ void w_prep(const float* __restrict__ W,
                       _Float16* __restrict__ WxT, _Float16* __restrict__ WhT) {
  int idx = blockIdx.x * 256 + threadIdx.x;
  if (idx < NUB * 64 * 256) {
    int k = idx & 255, cc = (idx >> 8) & 63, ub = idx >> 14;
    int unit = cc >> 2, g = cc & 3;
    int gcol = g * HID + ub * 16 + unit;
    WxT[idx] = (_Float16)W[k * 2048 + gcol];
  } else if (idx < NUB * 64 * 256 + NUB * 64 * 512) {
    int j = idx - NUB * 64 * 256;
    int k = j & 511, cc = (j >> 9) & 63, ub = j >> 15;
    int unit = cc >> 2, g = cc & 3;
    int gcol = g * HID + ub * 16 + unit;
    WhT[j] = (_Float16)W[(DIN + k) * 2048 + gcol];
  }
}

// segmentation (proven) + per-row-block max length (block = 32 VRs)
__global__ void seg_prep(const int* __restrict__ rst, int* __restrict__ tS,
                         int* __restrict__ segLen, int* __restrict__ maxLenB) {
  __shared__ int sMax[NRB];
  const int b = threadIdx.x;                  // 64 threads, 1 block
  if (b < NRB) sMax[b] = 0;
  __syncthreads();
  int cut[NCH + 1];
  cut[0] = 0; cut[NCH] = TSTEPS;
  for (int c = 1; c < NCH; ++c) {
    int t = c * 64;
    while (t < TSTEPS && rst[t * BATCH + b] == 0) ++t;
    cut[c] = t;
  }
  for (int c = 1; c < NCH; ++c) if (cut[c] < cut[c - 1]) cut[c] = cut[c - 1];
  for (int c = 0; c < NCH; ++c) {
    int vr = c * 64 + b;
    tS[vr] = cut[c];
    int L = cut[c + 1] - cut[c];
    segLen[vr] = L;
    atomicMax(&sMax[c * 2 + (b >> 5)], L);   // block rb = c*2 + (b>=32)
  }
  __syncthreads();
  if (b < NRB) maxLenB[b] = sMax[b];
}

// 512 WGs (2/CU co-resident: 42.5KB LDS, ~190 VGPR). Per-block dataflow sync
// via agent-atomic flags (proven). h slab staged once per WG per step via
// 16B sc0/sc1 loads (half the LLC op count of u64 atomics).
__global__ void __launch_bounds__(NTHR, 2)
lstm_persistent(const _Float16* __restrict__ xh,
                const int* __restrict__ rst,
                const float* __restrict__ bias,
                float* __restrict__ out,
                unsigned long long* __restrict__ hb,   // [2][VR][128] u64 (f16 h)
                unsigned* __restrict__ flags,          // [NWG][16] u32
                const _Float16* __restrict__ WxT,
                const _Float16* __restrict__ WhT,
                const int* __restrict__ tS,
                const int* __restrict__ segLen,
                const int* __restrict__ maxLenB) {
  __shared__ _Float16 hS[32 * HSST];          // 33.3 KB (full 32-row h slab)
  __shared__ float gateS[32 * GST];           // 8.6 KB
  __shared__ float biasS[64];

  const int tid = threadIdx.x, wg = blockIdx.x;
  const int rb = wg >> 5, ub = wg & 31;
  const int vr0 = rb * 32;
  const int lane = tid & 63, wave = tid >> 6;
  const int colA = lane & 15, klo = (lane >> 4) * 8;

  // ---- prologue: W fragments -> registers (wave w owns col-tile w) ----
  f16x8 wx[8], wh[16];
  {
    const _Float16* px = WxT + ((size_t)ub * 64 + wave * 16 + colA) * 256 + klo;
    const _Float16* ph = WhT + ((size_t)ub * 64 + wave * 16 + colA) * 512 + klo;
#pragma unroll
    for (int ch = 0; ch < 8; ++ch) wx[ch] = *(const f16x8*)(px + ch * 32);
#pragma unroll
    for (int ch = 0; ch < 16; ++ch) wh[ch] = *(const f16x8*)(ph + ch * 32);
  }
  if (tid < 64) {
    int unit = tid >> 2, g = tid & 3;
    biasS[tid] = bias[g * HID + ub * 16 + unit];
  }

  // MFMA-side per-lane row start times (rows rt*16+colA of this block)
  int tSr0 = tS[vr0 + colA];
  int tSr1 = tS[vr0 + 16 + colA];

  // cell-side: row crow, units 2p and 2p+1 (intra-wave: p in {2w,2w+1})
  const int crow = tid & 31, p = tid >> 5;
  const int vrc = vr0 + crow, bc = vrc & 63;
  const int tSc_ = tS[vrc], lenc_ = segLen[vrc];
  const int ML = maxLenB[rb];
  float cA = 0.f, cB = 0.f;

  __syncthreads();
  float bA[4], bB[4];
#pragma unroll
  for (int g = 0; g < 4; ++g) { bA[g] = biasS[8 * p + g]; bB[g] = biasS[8 * p + 4 + g]; }

  const int srow = tid >> 3, ss = tid & 7;    // h-slab staging assignment

  for (int k = 0; k < ML; ++k) {
    // ---- x-part (independent of h): loads + 16 MFMA, BEFORE the poll ----
    f32x4 acc0 = {0.f, 0.f, 0.f, 0.f}, acc1 = {0.f, 0.f, 0.f, 0.f};
    {
      int t0 = tSr0 + k; if (t0 > TSTEPS - 1) t0 = TSTEPS - 1;
      int t1 = tSr1 + k; if (t1 > TSTEPS - 1) t1 = TSTEPS - 1;
      const int b0 = (vr0 + colA) & 63, b1 = (vr0 + 16 + colA) & 63;
      const _Float16* x0 = xh + ((size_t)t0 * BATCH + b0) * DIN + klo;
      const _Float16* x1 = xh + ((size_t)t1 * BATCH + b1) * DIN + klo;
#pragma unroll
      for (int ch = 0; ch < 8; ++ch) {
        f16x8 a0 = *(const f16x8*)(x0 + ch * 32);
        f16x8 a1 = *(const f16x8*)(x1 + ch * 32);
        acc0 = MFMA16(a0, wx[ch], acc0);
        acc1 = MFMA16(a1, wx[ch], acc1);
      }
    }

    if (k) {
      // ---- acquire: poll only MY row-block's 32 producer flags ----
      if (tid < NUB) {
        const unsigned tgt = (unsigned)k;
        while (ALDU32(flags + (rb * NUB + tid) * 16) < tgt) __builtin_amdgcn_s_sleep(1);
      }
      __syncthreads();
      asm volatile("" ::: "memory");

      // ---- single-RT h slab: 8x dwordx4 sc0/sc1 per thread -> LDS ----
      {
        const char* hbase = (const char*)hb
            + (((size_t)(k & 1) * (VR * 128) + (size_t)(vr0 + srow) * 128) << 3)
            + ss * 16;
        f16x8 hq[8];
#pragma unroll
        for (int j = 0; j < 8; ++j) gld16_cc(hq[j], hbase + j * 128);
        asm volatile("s_waitcnt vmcnt(0)" ::: "memory");
        __builtin_amdgcn_sched_barrier(0);     // rule #18: pin uses after waitcnt
#pragma unroll
        for (int j = 0; j < 8; ++j)
          *(f16x8*)&hS[srow * HSST + ss * 8 + j * 64] = hq[j];
      }
      __syncthreads();                         // slab staged

      // ---- consume: 32 MFMA from LDS + wh regs ----
#pragma unroll
      for (int ch = 0; ch < 16; ++ch) {
        f16x8 a0 = *(const f16x8*)&hS[colA * HSST + ch * 32 + klo];
        f16x8 a1 = *(const f16x8*)&hS[(16 + colA) * HSST + ch * 32 + klo];
        acc0 = MFMA16(a0, wh[ch], acc0);
        acc1 = MFMA16(a1, wh[ch], acc1);
      }
    }

    // ---- stage gates: wave w writes cols 16w..16w+15 (intra-wave w/ cell) ----
#pragma unroll
    for (int rr = 0; rr < 4; ++rr) {
      int row0 = (lane >> 4) * 4 + rr;
      gateS[row0 * GST + wave * 16 + colA]        = acc0[rr];
      gateS[(16 + row0) * GST + wave * 16 + colA] = acc1[rr];
    }

    // ---- cell: row crow, units 2p & 2p+1 (gateS cols 8p..8p+7, same wave) ----
    float hn0, hn1;
    {
      int kidx = tSc_ + k + 1; if (kidx > TSTEPS - 1) kidx = TSTEPS - 1;
      float keep = 1.0f - (float)rst[kidx * BATCH + bc];
      const float* g = &gateS[crow * GST + 8 * p];
      float i0 = sigm(g[0] + bA[0]);
      float t0 = tanhf(g[1] + bA[1]);
      float f0 = sigm(g[2] + bA[2] + 1.0f);    // Haiku forget bias
      float o0 = sigm(g[3] + bA[3]);
      float i1 = sigm(g[4] + bB[0]);
      float t1 = tanhf(g[5] + bB[1]);
      float f1 = sigm(g[6] + bB[2] + 1.0f);
      float o1 = sigm(g[7] + bB[3]);
      float cn0 = f0 * cA + i0 * t0, cn1 = f1 * cB + i1 * t1;
      hn0 = o0 * tanhf(cn0); hn1 = o1 * tanhf(cn1);
      cA = cn0 * keep; cB = cn1 * keep;
      if (k + 1 < ML) {
        union { _Float16 f[2]; unsigned u; } cv;
        cv.f[0] = (_Float16)(hn0 * keep);
        cv.f[1] = (_Float16)(hn1 * keep);
        unsigned* hb32 = (unsigned*)(hb + (size_t)((k + 1) & 1) * (VR * 128) + (size_t)vrc * 128);
        ASTU32(hb32 + ub * 8 + p, cv.u);
      }
    }

    // ---- release: drain h stores (syncthreads emits vmcnt(0)) + 1 flag/WG ----
    __syncthreads();
    if (k + 1 < ML && tid == 0) ASTU32(flags + wg * 16, (unsigned)(k + 1));

    // ---- out store AFTER release: off the critical path ----
    if (k < lenc_) {
      f32x2 o2 = {hn0, hn1};
      *(f32x2*)&out[((size_t)(tSc_ + k) * BATCH + bc) * HID + ub * 16 + 2 * p] = o2;
    }
  }
}

extern "C" void kernel_launch(void* const* d_in, const int* in_sizes, int n_in,
                              void* d_out, int out_size, void* d_ws, size_t ws_size,
                              hipStream_t stream) {
  const float* x   = (const float*)d_in[0];
  const int*   rst = (const int*)d_in[1];
  const float* W   = (const float*)d_in[2];
  const float* b   = (const float*)d_in[3];
  float* out = (float*)d_out;
  char* ws = (char*)d_ws;

  // ws: flags(32K) | tS(2K) | segLen(2K) | maxLenB(4K pad) | hb(1M) | xh(16M) | WxT(1M) | WhT(2M)
  unsigned*           flags  = (unsigned*)(ws + 0);
  int*                tSp    = (int*)(ws + 32768);
  int*                segLen = (int*)(ws + 34816);
  int*                maxLenB= (int*)(ws + 36864);
  unsigned long long* hb     = (unsigned long long*)(ws + 40960);
  _Float16*           xh     = (_Float16*)(ws + 40960 + 1048576);
  _Float16*           WxT    = (_Float16*)(ws + 40960 + 1048576 + 16777216);
  _Float16*           WhT    = (_Float16*)(ws + 40960 + 1048576 + 16777216 + 1048576);

  hipMemsetAsync(ws, 0, 32768, stream);      // flags = 0 each launch (replay-safe)

  int n4 = TSTEPS * BATCH * DIN / 4;
  hipLaunchKernelGGL(conv_x, dim3(n4 / 256), dim3(256), 0, stream, x, xh, n4);
  hipLaunchKernelGGL(w_prep, dim3(6144), dim3(256), 0, stream, W, WxT, WhT);
  hipLaunchKernelGGL(seg_prep, dim3(1), dim3(64), 0, stream, rst, tSp, segLen, maxLenB);

  hipLaunchKernelGGL(lstm_persistent, dim3(NWG), dim3(NTHR), 0, stream,
                     xh, rst, b, out, hb, flags, WxT, WhT, tSp, segLen, maxLenB);
}